// Round 16
// baseline (2907.516 us; speedup 1.0000x reference)
//
#include <hip/hip_runtime.h>

typedef float f4 __attribute__((ext_vector_type(4)));

#define EPSF 1e-5f
#define CIN   256
#define COUT  512
#define HIN   28
#define WIN_  28
#define HO    14
#define WO    14
#define HWO   196
#define NPIX  6272              // 32*14*14 (one app)
#define MROWS 31360             // 5 apps * NPIX

#define BMr  64                 // rows per block
#define BNcT 128                // oc per block
#define BKC  16                 // k per step
#define LRA  64                 // A[k][row] stride
#define LRW  132                // W[k][oc] stride (pad)

#define NS1  144                // conv1: 9 taps * 16 chunks of 16
#define NS2  304                // conv2: 288 conv + 16 ds

// ---------------- prep kernels ----------------

__global__ __launch_bounds__(256)
void fold_bias_k(const float* __restrict__ g, const float* __restrict__ b,
                 const float* __restrict__ m, const float* __restrict__ v,
                 float* __restrict__ out)
{
  int oc = blockIdx.x * 256 + threadIdx.x;
  if (oc < COUT) {
    float s = g[oc] / sqrtf(v[oc] + EPSF);
    out[oc] = b[oc] - m[oc] * s;
  }
}

__global__ __launch_bounds__(256)
void fold_w_k(const float* __restrict__ w, const float* __restrict__ g,
              const float* __restrict__ v, float* __restrict__ out,
              int Ci, int taps)
{
  int idx = blockIdx.x * 256 + threadIdx.x;
  int total = taps * Ci * COUT;
  if (idx >= total) return;
  int oc  = idx % COUT;
  int c   = (idx / COUT) % Ci;
  int tap = idx / (COUT * Ci);
  float s = g[oc] / sqrtf(v[oc] + EPSF);
  out[idx] = w[((size_t)oc * Ci + c) * taps + tap] * s;
}

// ---------------- conv1 batched over 5 apps (3x3 s2 p1) ----------------
// Register-tiled GEMM: 64x128 tile, 128 threads (2 waves), thread = 8 rows x 8 oc.
// blockIdx.x = oc-tile (4); blockIdx.y = M-tile (490).

__global__ __launch_bounds__(128)
void conv1b_k(const float* __restrict__ XS,   // inp_s (4,32,256,28,28)
              const float* __restrict__ XC,   // inp_c (32,256,28,28)
              const float* __restrict__ W1,   // [tap][c][oc]
              float* __restrict__ IO)         // [31360][512]
{
  __shared__ float lA[BKC * LRA];
  __shared__ float lW[BKC * LRW];
  const int tid = threadIdx.x;
  const int tr = tid >> 4;          // 0..7 -> rows tr*8..+7
  const int tc = tid & 15;          // oc tc*4 and 64+tc*4
  const int oc0 = blockIdx.x * BNcT;
  const int rowBase = blockIdx.y * BMr;
  const int app = blockIdx.y / 98;  // 98 M-tiles per app (block-uniform)

  // A staging: one row, 8 k values (kq*8+j)
  const int grow = tid & 63;
  const int kq = tid >> 6;          // 0..1
  const int r = rowBase + grow;
  const int pp = r - app * NPIX;
  const int b = pp / HWO;
  const int hw = pp - b * HWO;
  const int ho = hw / WO, wo = hw - ho * WO;
  const float* xb = (app < 4) ? (XS + (size_t)(app * 32 + b) * (CIN * 784))
                              : (XC + (size_t)b * (CIN * 784));

  // W staging: 2 k-rows (wk, wk+8) x 8 oc
  const int wk = tid >> 4;          // 0..7
  const int woc = (tid & 15) * 8;

  float acc[8][8];
  #pragma unroll
  for (int i = 0; i < 8; i++)
    #pragma unroll
    for (int j = 0; j < 8; j++) acc[i][j] = 0.f;

  float ga[8]; f4 gw0, gw1, gw2, gw3;

  auto issue = [&](int s) {
    int tap = s >> 4, c0 = (s & 15) << 4;
    int kh = tap / 3, kw = tap - kh * 3;
    int hi = 2 * ho + kh - 1, wi = 2 * wo + kw - 1;
    bool v = ((unsigned)hi < (unsigned)HIN) && ((unsigned)wi < (unsigned)WIN_);
    const float* xp = xb + (size_t)(c0 + kq * 8) * 784 + hi * WIN_ + wi;
    #pragma unroll
    for (int j = 0; j < 8; j++) ga[j] = v ? xp[(size_t)j * 784] : 0.f;
    const float* wp = W1 + ((size_t)tap * CIN + c0 + wk) * COUT + oc0 + woc;
    gw0 = *(const f4*)wp;
    gw1 = *(const f4*)(wp + 4);
    const float* wp2 = wp + (size_t)8 * COUT;
    gw2 = *(const f4*)wp2;
    gw3 = *(const f4*)(wp2 + 4);
  };

  auto write_lds = [&]() {
    #pragma unroll
    for (int j = 0; j < 8; j++) lA[(kq * 8 + j) * LRA + grow] = ga[j];
    *(f4*)&lW[wk * LRW + woc] = gw0;
    *(f4*)&lW[wk * LRW + woc + 4] = gw1;
    *(f4*)&lW[(wk + 8) * LRW + woc] = gw2;
    *(f4*)&lW[(wk + 8) * LRW + woc + 4] = gw3;
  };

  auto compute = [&]() {
    #pragma unroll
    for (int k = 0; k < BKC; k++) {
      f4 a0 = *(const f4*)&lA[k * LRA + tr * 8];
      f4 a1 = *(const f4*)&lA[k * LRA + tr * 8 + 4];
      f4 w0 = *(const f4*)&lW[k * LRW + tc * 4];
      f4 w1 = *(const f4*)&lW[k * LRW + 64 + tc * 4];
      #pragma unroll
      for (int i = 0; i < 4; i++)
        #pragma unroll
        for (int j = 0; j < 4; j++) {
          acc[i][j]         = fmaf(a0[i], w0[j], acc[i][j]);
          acc[i][j + 4]     = fmaf(a0[i], w1[j], acc[i][j + 4]);
          acc[i + 4][j]     = fmaf(a1[i], w0[j], acc[i + 4][j]);
          acc[i + 4][j + 4] = fmaf(a1[i], w1[j], acc[i + 4][j + 4]);
        }
    }
  };

  issue(0);
  for (int s = 0; s < NS1; ++s) {
    __syncthreads();
    write_lds();
    __syncthreads();
    if (s + 1 < NS1) issue(s + 1);
    compute();
  }

  #pragma unroll
  for (int i = 0; i < 8; i++) {
    int row = rowBase + tr * 8 + i;
    f4 v0 = {acc[i][0], acc[i][1], acc[i][2], acc[i][3]};
    f4 v1 = {acc[i][4], acc[i][5], acc[i][6], acc[i][7]};
    *(f4*)&IO[(size_t)row * COUT + oc0 + tc * 4] = v0;
    *(f4*)&IO[(size_t)row * COUT + oc0 + 64 + tc * 4] = v1;
  }
}

// ---------------- layer-1 scan ----------------

__global__ __launch_bounds__(256)
void scan1_k(const float* __restrict__ IO, const float* __restrict__ b1v,
             const float* __restrict__ vth1,
             unsigned char* __restrict__ SP,   // [4][NPIX][512] u8
             float* __restrict__ ACT)          // [NPIX][512]
{
  int idx = blockIdx.x * 256 + threadIdx.x;
  int oc = idx & 511, pix = idx >> 9;
  int hw = pix % HWO;
  float b1 = b1v[oc], vt = vth1[oc * HWO + hw];
  float mem = 0.f; int m1 = 0;
  #pragma unroll
  for (int t = 0; t < 4; ++t) {
    float cur = IO[((size_t)t * NPIX + pix) * 512 + oc] + b1;
    mem += cur;
    float sp = (mem >= vt) ? 1.f : 0.f;
    mem -= sp * vt;
    m1 += (sp > 0.f) ? 1 : 0;
    SP[((size_t)t * NPIX + pix) * 512 + oc] = (unsigned char)sp;
  }
  float a = IO[((size_t)4 * NPIX + pix) * 512 + oc] + b1;
  a = a > 0.f ? a : 0.f;
  ACT[(size_t)pix * 512 + oc] = (m1 > 0) ? a : 0.f;
}

// ---------------- conv2 batched (3x3 s1 p1) + ds (1x1 s2) fused ----------------

__global__ __launch_bounds__(128)
void conv2b_k(const unsigned char* __restrict__ SP,
              const float* __restrict__ ACT,
              const float* __restrict__ XS,
              const float* __restrict__ XC,
              const float* __restrict__ W2,
              const float* __restrict__ WD,
              float* __restrict__ IO)
{
  __shared__ float lA[BKC * LRA];
  __shared__ float lW[BKC * LRW];
  const int tid = threadIdx.x;
  const int tr = tid >> 4;
  const int tc = tid & 15;
  const int oc0 = blockIdx.x * BNcT;
  const int rowBase = blockIdx.y * BMr;
  const int app = blockIdx.y / 98;

  const int grow = tid & 63;
  const int kq = tid >> 6;
  const int r = rowBase + grow;
  const int pp = r - app * NPIX;
  const int b = pp / HWO;
  const int hw = pp - b * HWO;
  const int ho = hw / WO, wo = hw - ho * WO;
  const float* xb = (app < 4) ? (XS + (size_t)(app * 32 + b) * (CIN * 784))
                              : (XC + (size_t)b * (CIN * 784));
  const unsigned char* spb = SP + (size_t)app * NPIX * 512;

  const int wk = tid >> 4;
  const int woc = (tid & 15) * 8;

  float acc[8][8];
  #pragma unroll
  for (int i = 0; i < 8; i++)
    #pragma unroll
    for (int j = 0; j < 8; j++) acc[i][j] = 0.f;

  float ga[8]; f4 gw0, gw1, gw2, gw3;

  auto issue = [&](int s) {
    if (s < 288) {
      int tap = s >> 5, c0 = (s & 31) << 4;
      int kh = tap / 3, kw = tap - kh * 3;
      int hi = ho + kh - 1, wi = wo + kw - 1;
      bool v = ((unsigned)hi < (unsigned)HO) && ((unsigned)wi < (unsigned)WO);
      int pix2 = b * HWO + hi * WO + wi;
      int c = c0 + kq * 8;
      if (app < 4) {
        unsigned u0 = 0, u1 = 0;
        if (v) {
          const unsigned* sp32 = (const unsigned*)(spb + (size_t)pix2 * 512 + c);
          u0 = sp32[0]; u1 = sp32[1];
        }
        #pragma unroll
        for (int j = 0; j < 4; j++) {
          ga[j]     = (float)((u0 >> (8 * j)) & 255u);
          ga[j + 4] = (float)((u1 >> (8 * j)) & 255u);
        }
      } else {
        f4 v0 = {0.f,0.f,0.f,0.f}, v1 = {0.f,0.f,0.f,0.f};
        if (v) {
          const float* ap = ACT + (size_t)pix2 * 512 + c;
          v0 = *(const f4*)ap; v1 = *(const f4*)(ap + 4);
        }
        #pragma unroll
        for (int j = 0; j < 4; j++) { ga[j] = v0[j]; ga[j + 4] = v1[j]; }
      }
      const float* wp = W2 + ((size_t)tap * COUT + c0 + wk) * COUT + oc0 + woc;
      gw0 = *(const f4*)wp;
      gw1 = *(const f4*)(wp + 4);
      const float* wp2 = wp + (size_t)8 * COUT;
      gw2 = *(const f4*)wp2;
      gw3 = *(const f4*)(wp2 + 4);
    } else {
      int c0 = (s - 288) << 4;
      const float* xp = xb + (size_t)(c0 + kq * 8) * 784 + 2 * ho * WIN_ + 2 * wo;
      #pragma unroll
      for (int j = 0; j < 8; j++) ga[j] = xp[(size_t)j * 784];
      const float* wp = WD + (size_t)(c0 + wk) * COUT + oc0 + woc;
      gw0 = *(const f4*)wp;
      gw1 = *(const f4*)(wp + 4);
      const float* wp2 = wp + (size_t)8 * COUT;
      gw2 = *(const f4*)wp2;
      gw3 = *(const f4*)(wp2 + 4);
    }
  };

  auto write_lds = [&]() {
    #pragma unroll
    for (int j = 0; j < 8; j++) lA[(kq * 8 + j) * LRA + grow] = ga[j];
    *(f4*)&lW[wk * LRW + woc] = gw0;
    *(f4*)&lW[wk * LRW + woc + 4] = gw1;
    *(f4*)&lW[(wk + 8) * LRW + woc] = gw2;
    *(f4*)&lW[(wk + 8) * LRW + woc + 4] = gw3;
  };

  auto compute = [&]() {
    #pragma unroll
    for (int k = 0; k < BKC; k++) {
      f4 a0 = *(const f4*)&lA[k * LRA + tr * 8];
      f4 a1 = *(const f4*)&lA[k * LRA + tr * 8 + 4];
      f4 w0 = *(const f4*)&lW[k * LRW + tc * 4];
      f4 w1 = *(const f4*)&lW[k * LRW + 64 + tc * 4];
      #pragma unroll
      for (int i = 0; i < 4; i++)
        #pragma unroll
        for (int j = 0; j < 4; j++) {
          acc[i][j]         = fmaf(a0[i], w0[j], acc[i][j]);
          acc[i][j + 4]     = fmaf(a0[i], w1[j], acc[i][j + 4]);
          acc[i + 4][j]     = fmaf(a1[i], w0[j], acc[i + 4][j]);
          acc[i + 4][j + 4] = fmaf(a1[i], w1[j], acc[i + 4][j + 4]);
        }
    }
  };

  issue(0);
  for (int s = 0; s < NS2; ++s) {
    __syncthreads();
    write_lds();
    __syncthreads();
    if (s + 1 < NS2) issue(s + 1);
    compute();
  }

  #pragma unroll
  for (int i = 0; i < 8; i++) {
    int row = rowBase + tr * 8 + i;
    f4 v0 = {acc[i][0], acc[i][1], acc[i][2], acc[i][3]};
    f4 v1 = {acc[i][4], acc[i][5], acc[i][6], acc[i][7]};
    *(f4*)&IO[(size_t)row * COUT + oc0 + tc * 4] = v0;
    *(f4*)&IO[(size_t)row * COUT + oc0 + 64 + tc * 4] = v1;
  }
}

// ---------------- final scan + outputs (NCHW) ----------------

__global__ __launch_bounds__(256)
void final_k(const float* __restrict__ IO, const float* __restrict__ b2v,
             const float* __restrict__ bdv, const float* __restrict__ vthif,
             float* __restrict__ out0, float* __restrict__ out1,
             float* __restrict__ out2)
{
  int idx = blockIdx.x * 256 + threadIdx.x;
  int oc = idx & 511, pix = idx >> 9;
  int hw = pix % HWO, b = pix / HWO;
  float bias = b2v[oc] + bdv[oc];
  float vt = vthif[oc * HWO + hw];
  float memf = 0.f; int m3 = 0; float o3 = 0.f, os3 = 0.f;
  #pragma unroll
  for (int t = 0; t < 4; ++t) {
    float os = IO[((size_t)t * NPIX + pix) * 512 + oc] + bias;
    memf += os;
    float sp = (memf >= vt) ? 1.f : 0.f;
    memf -= sp * vt;
    m3 += (sp > 0.f) ? 1 : 0;
    if (t == 3) { o3 = sp; os3 = os; }
  }
  size_t oidx = ((size_t)b * COUT + oc) * HWO + hw;
  out0[oidx] = o3;
  out1[oidx] = os3;
  float av = IO[((size_t)4 * NPIX + pix) * 512 + oc] + bias;
  av = av > 0.f ? av : 0.f;
  out2[oidx] = (m3 > 0) ? av : 0.f;
}

// ---------------- launcher ----------------

extern "C" void kernel_launch(void* const* d_in, const int* in_sizes, int n_in,
                              void* d_out, int out_size, void* d_ws, size_t ws_size,
                              hipStream_t stream)
{
  const float* inp_s = (const float*)d_in[0];
  const float* inp_c = (const float*)d_in[2];
  const float* w1    = (const float*)d_in[3];
  const float* w2    = (const float*)d_in[4];
  const float* wd    = (const float*)d_in[5];
  const float* bn1g = (const float*)d_in[6],  *bn1b = (const float*)d_in[7];
  const float* bn1m = (const float*)d_in[8],  *bn1v = (const float*)d_in[9];
  const float* bn2g = (const float*)d_in[10], *bn2b = (const float*)d_in[11];
  const float* bn2m = (const float*)d_in[12], *bn2v = (const float*)d_in[13];
  const float* dsg  = (const float*)d_in[14], *dsb  = (const float*)d_in[15];
  const float* dsm  = (const float*)d_in[16], *dsv  = (const float*)d_in[17];
  const float* vth1  = (const float*)d_in[18];
  const float* vthif = (const float*)d_in[21];

  float* ws = (float*)d_ws;
  size_t off = 0;
  float* W1T = ws + off; off += (size_t)9 * CIN * COUT;
  float* W2T = ws + off; off += (size_t)9 * COUT * COUT;
  float* WDT = ws + off; off += (size_t)CIN * COUT;
  float* B1V = ws + off; off += COUT;
  float* B2V = ws + off; off += COUT;
  float* BDV = ws + off; off += COUT;
  float* IO  = ws + off; off += (size_t)MROWS * COUT;
  float* ACT = ws + off; off += (size_t)NPIX * COUT;
  unsigned char* SP = (unsigned char*)(ws + off);
  // total ~104.6 MB, under the R1-proven 117.4 MB bound

  float* out0 = (float*)d_out;
  float* out1 = out0 + (size_t)NPIX * COUT;
  float* out2 = out1 + (size_t)NPIX * COUT;

  fold_bias_k<<<2, 256, 0, stream>>>(bn1g, bn1b, bn1m, bn1v, B1V);
  fold_bias_k<<<2, 256, 0, stream>>>(bn2g, bn2b, bn2m, bn2v, B2V);
  fold_bias_k<<<2, 256, 0, stream>>>(dsg,  dsb,  dsm,  dsv,  BDV);
  fold_w_k<<<(9 * CIN * COUT + 255) / 256, 256, 0, stream>>>(w1, bn1g, bn1v, W1T, CIN, 9);
  fold_w_k<<<(9 * COUT * COUT + 255) / 256, 256, 0, stream>>>(w2, bn2g, bn2v, W2T, COUT, 9);
  fold_w_k<<<(CIN * COUT + 255) / 256, 256, 0, stream>>>(wd, dsg, dsv, WDT, CIN, 1);

  dim3 cgrid(COUT / BNcT, MROWS / BMr);         // 4 x 490, 128-thread blocks
  const int scanGrid = (NPIX * COUT) / 256;

  conv1b_k<<<cgrid, 128, 0, stream>>>(inp_s, inp_c, W1T, IO);
  scan1_k<<<scanGrid, 256, 0, stream>>>(IO, B1V, vth1, SP, ACT);
  conv2b_k<<<cgrid, 128, 0, stream>>>(SP, ACT, inp_s, inp_c, W2T, WDT, IO);
  final_k<<<scanGrid, 256, 0, stream>>>(IO, B2V, BDV, vthif, out0, out1, out2);
}

// Round 17
// 2802.613 us; speedup vs baseline: 1.0374x; 1.0374x over previous
//
#include <hip/hip_runtime.h>

typedef float f4 __attribute__((ext_vector_type(4)));

#define EPSF 1e-5f
#define CIN   256
#define COUT  512
#define HIN   28
#define WIN_  28
#define HO    14
#define WO    14
#define HWO   196
#define NPIX  6272              // 32*14*14 (one app)
#define MROWS 31360             // 5 apps * NPIX

#define BNcT 128                // oc per block (both kernels)
#define BKC  16                 // k per step
#define LRW  132                // W[k][oc] stride (pad)

// conv1: 128x128 tile (R15-best)
#define BM1  128
#define LRA1 128
#define NS1  144                // 9 taps * 16 chunks of 16
// conv2: 64x128 tile (R14-best)
#define BM2  64
#define LRA2 64
#define NS2  304                // 288 conv + 16 ds

// ---------------- prep kernels ----------------

__global__ __launch_bounds__(256)
void fold_bias_k(const float* __restrict__ g, const float* __restrict__ b,
                 const float* __restrict__ m, const float* __restrict__ v,
                 float* __restrict__ out)
{
  int oc = blockIdx.x * 256 + threadIdx.x;
  if (oc < COUT) {
    float s = g[oc] / sqrtf(v[oc] + EPSF);
    out[oc] = b[oc] - m[oc] * s;
  }
}

__global__ __launch_bounds__(256)
void fold_w_k(const float* __restrict__ w, const float* __restrict__ g,
              const float* __restrict__ v, float* __restrict__ out,
              int Ci, int taps)
{
  int idx = blockIdx.x * 256 + threadIdx.x;
  int total = taps * Ci * COUT;
  if (idx >= total) return;
  int oc  = idx % COUT;
  int c   = (idx / COUT) % Ci;
  int tap = idx / (COUT * Ci);
  float s = g[oc] / sqrtf(v[oc] + EPSF);
  out[idx] = w[((size_t)oc * Ci + c) * taps + tap] * s;
}

// ---------------- conv1 batched over 5 apps (3x3 s2 p1) ----------------
// R15-best: 128x128 tile, 256 threads, thread = 8 rows x 8 oc.
// blockIdx.x = oc-tile (4); blockIdx.y = M-tile (245).

__global__ __launch_bounds__(256)
void conv1b_k(const float* __restrict__ XS,   // inp_s (4,32,256,28,28)
              const float* __restrict__ XC,   // inp_c (32,256,28,28)
              const float* __restrict__ W1,   // [tap][c][oc]
              float* __restrict__ IO)         // [31360][512]
{
  __shared__ float lA[BKC * LRA1];
  __shared__ float lW[BKC * LRW];
  const int tid = threadIdx.x;
  const int tr = tid >> 4;          // 0..15 -> rows tr*8..+7
  const int tc = tid & 15;          // oc tc*4 and 64+tc*4
  const int oc0 = blockIdx.x * BNcT;
  const int rowBase = blockIdx.y * BM1;
  const int app = blockIdx.y / 49;  // block-uniform

  // A staging role: one row, 8 k values
  const int grow = tid & 127;
  const int kq = tid >> 7;          // 0..1 -> k = kq*8 + j
  const int r = rowBase + grow;
  const int pp = r - app * NPIX;
  const int b = pp / HWO;
  const int hw = pp - b * HWO;
  const int ho = hw / WO, wo = hw - ho * WO;
  const float* xb = (app < 4) ? (XS + (size_t)(app * 32 + b) * (CIN * 784))
                              : (XC + (size_t)b * (CIN * 784));

  // W staging role
  const int wk = tid >> 4;          // k row 0..15
  const int woc = (tid & 15) * 8;   // 8 oc

  float acc[8][8];
  #pragma unroll
  for (int i = 0; i < 8; i++)
    #pragma unroll
    for (int j = 0; j < 8; j++) acc[i][j] = 0.f;

  float ga[8]; f4 gw0, gw1;

  auto issue = [&](int s) {
    int tap = s >> 4, c0 = (s & 15) << 4;
    int kh = tap / 3, kw = tap - kh * 3;
    int hi = 2 * ho + kh - 1, wi = 2 * wo + kw - 1;
    bool v = ((unsigned)hi < (unsigned)HIN) && ((unsigned)wi < (unsigned)WIN_);
    const float* xp = xb + (size_t)(c0 + kq * 8) * 784 + hi * WIN_ + wi;
    #pragma unroll
    for (int j = 0; j < 8; j++) ga[j] = v ? xp[(size_t)j * 784] : 0.f;
    const float* wp = W1 + ((size_t)tap * CIN + c0 + wk) * COUT + oc0 + woc;
    gw0 = *(const f4*)wp;
    gw1 = *(const f4*)(wp + 4);
  };

  auto write_lds = [&]() {
    #pragma unroll
    for (int j = 0; j < 8; j++) lA[(kq * 8 + j) * LRA1 + grow] = ga[j];
    *(f4*)&lW[wk * LRW + woc] = gw0;
    *(f4*)&lW[wk * LRW + woc + 4] = gw1;
  };

  auto compute = [&]() {
    #pragma unroll
    for (int k = 0; k < BKC; k++) {
      f4 a0 = *(const f4*)&lA[k * LRA1 + tr * 8];
      f4 a1 = *(const f4*)&lA[k * LRA1 + tr * 8 + 4];
      f4 w0 = *(const f4*)&lW[k * LRW + tc * 4];
      f4 w1 = *(const f4*)&lW[k * LRW + 64 + tc * 4];
      #pragma unroll
      for (int i = 0; i < 4; i++)
        #pragma unroll
        for (int j = 0; j < 4; j++) {
          acc[i][j]         = fmaf(a0[i], w0[j], acc[i][j]);
          acc[i][j + 4]     = fmaf(a0[i], w1[j], acc[i][j + 4]);
          acc[i + 4][j]     = fmaf(a1[i], w0[j], acc[i + 4][j]);
          acc[i + 4][j + 4] = fmaf(a1[i], w1[j], acc[i + 4][j + 4]);
        }
    }
  };

  issue(0);
  for (int s = 0; s < NS1; ++s) {
    __syncthreads();
    write_lds();
    __syncthreads();
    if (s + 1 < NS1) issue(s + 1);
    compute();
  }

  #pragma unroll
  for (int i = 0; i < 8; i++) {
    int row = rowBase + tr * 8 + i;
    f4 v0 = {acc[i][0], acc[i][1], acc[i][2], acc[i][3]};
    f4 v1 = {acc[i][4], acc[i][5], acc[i][6], acc[i][7]};
    *(f4*)&IO[(size_t)row * COUT + oc0 + tc * 4] = v0;
    *(f4*)&IO[(size_t)row * COUT + oc0 + 64 + tc * 4] = v1;
  }
}

// ---------------- layer-1 scan ----------------

__global__ __launch_bounds__(256)
void scan1_k(const float* __restrict__ IO, const float* __restrict__ b1v,
             const float* __restrict__ vth1,
             unsigned char* __restrict__ SP,   // [4][NPIX][512] u8
             float* __restrict__ ACT)          // [NPIX][512]
{
  int idx = blockIdx.x * 256 + threadIdx.x;
  int oc = idx & 511, pix = idx >> 9;
  int hw = pix % HWO;
  float b1 = b1v[oc], vt = vth1[oc * HWO + hw];
  float mem = 0.f; int m1 = 0;
  #pragma unroll
  for (int t = 0; t < 4; ++t) {
    float cur = IO[((size_t)t * NPIX + pix) * 512 + oc] + b1;
    mem += cur;
    float sp = (mem >= vt) ? 1.f : 0.f;
    mem -= sp * vt;
    m1 += (sp > 0.f) ? 1 : 0;
    SP[((size_t)t * NPIX + pix) * 512 + oc] = (unsigned char)sp;
  }
  float a = IO[((size_t)4 * NPIX + pix) * 512 + oc] + b1;
  a = a > 0.f ? a : 0.f;
  ACT[(size_t)pix * 512 + oc] = (m1 > 0) ? a : 0.f;
}

// ---------------- conv2 batched (3x3 s1 p1) + ds (1x1 s2) fused ----------------
// R14-best: 64x128 tile, 256 threads, thread = 4 rows x 8 oc (VGPR ~52).
// blockIdx.x = oc-tile (4); blockIdx.y = M-tile (490).

__global__ __launch_bounds__(256)
void conv2b_k(const unsigned char* __restrict__ SP,
              const float* __restrict__ ACT,
              const float* __restrict__ XS,
              const float* __restrict__ XC,
              const float* __restrict__ W2,
              const float* __restrict__ WD,
              float* __restrict__ IO)
{
  __shared__ float lA[BKC * LRA2];
  __shared__ float lW[BKC * LRW];
  const int tid = threadIdx.x;
  const int tr = tid >> 4;
  const int tc = tid & 15;
  const int oc0 = blockIdx.x * BNcT;
  const int rowBase = blockIdx.y * BM2;
  const int app = blockIdx.y / 98;

  const int grow = tid & 63;
  const int kq = tid >> 6;
  const int r = rowBase + grow;
  const int pp = r - app * NPIX;
  const int b = pp / HWO;
  const int hw = pp - b * HWO;
  const int ho = hw / WO, wo = hw - ho * WO;
  const float* xb = (app < 4) ? (XS + (size_t)(app * 32 + b) * (CIN * 784))
                              : (XC + (size_t)b * (CIN * 784));
  const unsigned char* spb = SP + (size_t)app * NPIX * 512;

  const int wk = tid >> 4;
  const int woc = (tid & 15) * 8;

  float acc[4][8];
  #pragma unroll
  for (int i = 0; i < 4; i++)
    #pragma unroll
    for (int j = 0; j < 8; j++) acc[i][j] = 0.f;

  f4 ga, gw0, gw1;

  auto issue = [&](int s) {
    if (s < 288) {
      int tap = s >> 5, c0 = (s & 31) << 4;
      int kh = tap / 3, kw = tap - kh * 3;
      int hi = ho + kh - 1, wi = wo + kw - 1;
      bool v = ((unsigned)hi < (unsigned)HO) && ((unsigned)wi < (unsigned)WO);
      int pix2 = b * HWO + hi * WO + wi;
      int c = c0 + kq * 4;
      if (app < 4) {
        unsigned u = 0;
        if (v) u = *(const unsigned*)(spb + (size_t)pix2 * 512 + c);
        #pragma unroll
        for (int j = 0; j < 4; j++) ga[j] = (float)((u >> (8 * j)) & 255u);
      } else {
        f4 val = {0.f, 0.f, 0.f, 0.f};
        if (v) val = *(const f4*)(ACT + (size_t)pix2 * 512 + c);
        ga = val;
      }
      const float* wp = W2 + ((size_t)tap * COUT + c0 + wk) * COUT + oc0 + woc;
      gw0 = *(const f4*)wp;
      gw1 = *(const f4*)(wp + 4);
    } else {
      int c0 = (s - 288) << 4;
      const float* xp = xb + (size_t)(c0 + kq * 4) * 784 + 2 * ho * WIN_ + 2 * wo;
      #pragma unroll
      for (int j = 0; j < 4; j++) ga[j] = xp[(size_t)j * 784];
      const float* wp = WD + (size_t)(c0 + wk) * COUT + oc0 + woc;
      gw0 = *(const f4*)wp;
      gw1 = *(const f4*)(wp + 4);
    }
  };

  auto write_lds = [&]() {
    #pragma unroll
    for (int j = 0; j < 4; j++) lA[(kq * 4 + j) * LRA2 + grow] = ga[j];
    *(f4*)&lW[wk * LRW + woc] = gw0;
    *(f4*)&lW[wk * LRW + woc + 4] = gw1;
  };

  auto compute = [&]() {
    #pragma unroll
    for (int k = 0; k < BKC; k++) {
      f4 a  = *(const f4*)&lA[k * LRA2 + tr * 4];
      f4 w0 = *(const f4*)&lW[k * LRW + tc * 4];
      f4 w1 = *(const f4*)&lW[k * LRW + 64 + tc * 4];
      #pragma unroll
      for (int i = 0; i < 4; i++)
        #pragma unroll
        for (int j = 0; j < 4; j++) {
          acc[i][j]     = fmaf(a[i], w0[j], acc[i][j]);
          acc[i][j + 4] = fmaf(a[i], w1[j], acc[i][j + 4]);
        }
    }
  };

  issue(0);
  for (int s = 0; s < NS2; ++s) {
    __syncthreads();
    write_lds();
    __syncthreads();
    if (s + 1 < NS2) issue(s + 1);
    compute();
  }

  #pragma unroll
  for (int i = 0; i < 4; i++) {
    int row = rowBase + tr * 4 + i;
    f4 v0 = {acc[i][0], acc[i][1], acc[i][2], acc[i][3]};
    f4 v1 = {acc[i][4], acc[i][5], acc[i][6], acc[i][7]};
    *(f4*)&IO[(size_t)row * COUT + oc0 + tc * 4] = v0;
    *(f4*)&IO[(size_t)row * COUT + oc0 + 64 + tc * 4] = v1;
  }
}

// ---------------- final scan + outputs (NCHW) ----------------

__global__ __launch_bounds__(256)
void final_k(const float* __restrict__ IO, const float* __restrict__ b2v,
             const float* __restrict__ bdv, const float* __restrict__ vthif,
             float* __restrict__ out0, float* __restrict__ out1,
             float* __restrict__ out2)
{
  int idx = blockIdx.x * 256 + threadIdx.x;
  int oc = idx & 511, pix = idx >> 9;
  int hw = pix % HWO, b = pix / HWO;
  float bias = b2v[oc] + bdv[oc];
  float vt = vthif[oc * HWO + hw];
  float memf = 0.f; int m3 = 0; float o3 = 0.f, os3 = 0.f;
  #pragma unroll
  for (int t = 0; t < 4; ++t) {
    float os = IO[((size_t)t * NPIX + pix) * 512 + oc] + bias;
    memf += os;
    float sp = (memf >= vt) ? 1.f : 0.f;
    memf -= sp * vt;
    m3 += (sp > 0.f) ? 1 : 0;
    if (t == 3) { o3 = sp; os3 = os; }
  }
  size_t oidx = ((size_t)b * COUT + oc) * HWO + hw;
  out0[oidx] = o3;
  out1[oidx] = os3;
  float av = IO[((size_t)4 * NPIX + pix) * 512 + oc] + bias;
  av = av > 0.f ? av : 0.f;
  out2[oidx] = (m3 > 0) ? av : 0.f;
}

// ---------------- launcher ----------------

extern "C" void kernel_launch(void* const* d_in, const int* in_sizes, int n_in,
                              void* d_out, int out_size, void* d_ws, size_t ws_size,
                              hipStream_t stream)
{
  const float* inp_s = (const float*)d_in[0];
  const float* inp_c = (const float*)d_in[2];
  const float* w1    = (const float*)d_in[3];
  const float* w2    = (const float*)d_in[4];
  const float* wd    = (const float*)d_in[5];
  const float* bn1g = (const float*)d_in[6],  *bn1b = (const float*)d_in[7];
  const float* bn1m = (const float*)d_in[8],  *bn1v = (const float*)d_in[9];
  const float* bn2g = (const float*)d_in[10], *bn2b = (const float*)d_in[11];
  const float* bn2m = (const float*)d_in[12], *bn2v = (const float*)d_in[13];
  const float* dsg  = (const float*)d_in[14], *dsb  = (const float*)d_in[15];
  const float* dsm  = (const float*)d_in[16], *dsv  = (const float*)d_in[17];
  const float* vth1  = (const float*)d_in[18];
  const float* vthif = (const float*)d_in[21];

  float* ws = (float*)d_ws;
  size_t off = 0;
  float* W1T = ws + off; off += (size_t)9 * CIN * COUT;
  float* W2T = ws + off; off += (size_t)9 * COUT * COUT;
  float* WDT = ws + off; off += (size_t)CIN * COUT;
  float* B1V = ws + off; off += COUT;
  float* B2V = ws + off; off += COUT;
  float* BDV = ws + off; off += COUT;
  float* IO  = ws + off; off += (size_t)MROWS * COUT;
  float* ACT = ws + off; off += (size_t)NPIX * COUT;
  unsigned char* SP = (unsigned char*)(ws + off);
  // total ~104.6 MB, under the R1-proven 117.4 MB bound

  float* out0 = (float*)d_out;
  float* out1 = out0 + (size_t)NPIX * COUT;
  float* out2 = out1 + (size_t)NPIX * COUT;

  fold_bias_k<<<2, 256, 0, stream>>>(bn1g, bn1b, bn1m, bn1v, B1V);
  fold_bias_k<<<2, 256, 0, stream>>>(bn2g, bn2b, bn2m, bn2v, B2V);
  fold_bias_k<<<2, 256, 0, stream>>>(dsg,  dsb,  dsm,  dsv,  BDV);
  fold_w_k<<<(9 * CIN * COUT + 255) / 256, 256, 0, stream>>>(w1, bn1g, bn1v, W1T, CIN, 9);
  fold_w_k<<<(9 * COUT * COUT + 255) / 256, 256, 0, stream>>>(w2, bn2g, bn2v, W2T, COUT, 9);
  fold_w_k<<<(CIN * COUT + 255) / 256, 256, 0, stream>>>(wd, dsg, dsv, WDT, CIN, 1);

  dim3 cgrid1(COUT / BNcT, MROWS / BM1);        // 4 x 245
  dim3 cgrid2(COUT / BNcT, MROWS / BM2);        // 4 x 490
  const int scanGrid = (NPIX * COUT) / 256;

  conv1b_k<<<cgrid1, 256, 0, stream>>>(inp_s, inp_c, W1T, IO);
  scan1_k<<<scanGrid, 256, 0, stream>>>(IO, B1V, vth1, SP, ACT);
  conv2b_k<<<cgrid2, 256, 0, stream>>>(SP, ACT, inp_s, inp_c, W2T, WDT, IO);
  final_k<<<scanGrid, 256, 0, stream>>>(IO, B2V, BDV, vthif, out0, out1, out2);
}

// Round 18
// 2762.931 us; speedup vs baseline: 1.0523x; 1.0144x over previous
//
#include <hip/hip_runtime.h>

typedef float f4 __attribute__((ext_vector_type(4)));

#define EPSF 1e-5f
#define CIN   256
#define COUT  512
#define HIN   28
#define WIN_  28
#define HO    14
#define WO    14
#define HWO   196
#define NPIX  6272              // 32*14*14 (one app)
#define MROWS 31360             // 5 apps * NPIX

#define BMr  128                // rows per block
#define BNcT 128                // oc per block
#define BKC  16                 // k per step
#define LRA  128                // A[k][row] stride
#define LRW  132                // W[k][oc] stride (pad)

#define NS1  144                // conv1: 9 taps * 16 chunks of 16
#define NS2  304                // conv2: 288 conv + 16 ds

// ---------------- prep kernels ----------------

__global__ __launch_bounds__(256)
void fold_bias_k(const float* __restrict__ g, const float* __restrict__ b,
                 const float* __restrict__ m, const float* __restrict__ v,
                 float* __restrict__ out)
{
  int oc = blockIdx.x * 256 + threadIdx.x;
  if (oc < COUT) {
    float s = g[oc] / sqrtf(v[oc] + EPSF);
    out[oc] = b[oc] - m[oc] * s;
  }
}

__global__ __launch_bounds__(256)
void fold_w_k(const float* __restrict__ w, const float* __restrict__ g,
              const float* __restrict__ v, float* __restrict__ out,
              int Ci, int taps)
{
  int idx = blockIdx.x * 256 + threadIdx.x;
  int total = taps * Ci * COUT;
  if (idx >= total) return;
  int oc  = idx % COUT;
  int c   = (idx / COUT) % Ci;
  int tap = idx / (COUT * Ci);
  float s = g[oc] / sqrtf(v[oc] + EPSF);
  out[idx] = w[((size_t)oc * Ci + c) * taps + tap] * s;
}

// ---------------- conv1 batched over 5 apps (3x3 s2 p1) ----------------
// Register-tiled GEMM: 128x128 tile, thread = 8 rows x 8 oc.
// blockIdx.x = oc-tile (4); blockIdx.y = M-tile (245).

__global__ __launch_bounds__(256)
void conv1b_k(const float* __restrict__ XS,   // inp_s (4,32,256,28,28)
              const float* __restrict__ XC,   // inp_c (32,256,28,28)
              const float* __restrict__ W1,   // [tap][c][oc]
              float* __restrict__ IO)         // [31360][512]
{
  __shared__ float lA[BKC * LRA];
  __shared__ float lW[BKC * LRW];
  const int tid = threadIdx.x;
  const int tr = tid >> 4;          // 0..15 -> rows tr*8..+7
  const int tc = tid & 15;          // oc tc*4 and 64+tc*4
  const int oc0 = blockIdx.x * BNcT;
  const int rowBase = blockIdx.y * BMr;
  const int app = blockIdx.y / 49;  // block-uniform

  // A staging role: one row, 8 k values
  const int grow = tid & 127;
  const int kq = tid >> 7;          // 0..1 -> k = kq*8 + j
  const int r = rowBase + grow;
  const int pp = r - app * NPIX;
  const int b = pp / HWO;
  const int hw = pp - b * HWO;
  const int ho = hw / WO, wo = hw - ho * WO;
  const float* xb = (app < 4) ? (XS + (size_t)(app * 32 + b) * (CIN * 784))
                              : (XC + (size_t)b * (CIN * 784));

  // W staging role
  const int wk = tid >> 4;          // k row 0..15
  const int woc = (tid & 15) * 8;   // 8 oc

  float acc[8][8];
  #pragma unroll
  for (int i = 0; i < 8; i++)
    #pragma unroll
    for (int j = 0; j < 8; j++) acc[i][j] = 0.f;

  float ga[8]; f4 gw0, gw1;

  auto issue = [&](int s) {
    int tap = s >> 4, c0 = (s & 15) << 4;
    int kh = tap / 3, kw = tap - kh * 3;
    int hi = 2 * ho + kh - 1, wi = 2 * wo + kw - 1;
    bool v = ((unsigned)hi < (unsigned)HIN) && ((unsigned)wi < (unsigned)WIN_);
    const float* xp = xb + (size_t)(c0 + kq * 8) * 784 + hi * WIN_ + wi;
    #pragma unroll
    for (int j = 0; j < 8; j++) ga[j] = v ? xp[(size_t)j * 784] : 0.f;
    const float* wp = W1 + ((size_t)tap * CIN + c0 + wk) * COUT + oc0 + woc;
    gw0 = *(const f4*)wp;
    gw1 = *(const f4*)(wp + 4);
  };

  auto write_lds = [&]() {
    #pragma unroll
    for (int j = 0; j < 8; j++) lA[(kq * 8 + j) * LRA + grow] = ga[j];
    *(f4*)&lW[wk * LRW + woc] = gw0;
    *(f4*)&lW[wk * LRW + woc + 4] = gw1;
  };

  auto compute = [&]() {
    #pragma unroll
    for (int k = 0; k < BKC; k++) {
      f4 a0 = *(const f4*)&lA[k * LRA + tr * 8];
      f4 a1 = *(const f4*)&lA[k * LRA + tr * 8 + 4];
      f4 w0 = *(const f4*)&lW[k * LRW + tc * 4];
      f4 w1 = *(const f4*)&lW[k * LRW + 64 + tc * 4];
      #pragma unroll
      for (int i = 0; i < 4; i++)
        #pragma unroll
        for (int j = 0; j < 4; j++) {
          acc[i][j]         = fmaf(a0[i], w0[j], acc[i][j]);
          acc[i][j + 4]     = fmaf(a0[i], w1[j], acc[i][j + 4]);
          acc[i + 4][j]     = fmaf(a1[i], w0[j], acc[i + 4][j]);
          acc[i + 4][j + 4] = fmaf(a1[i], w1[j], acc[i + 4][j + 4]);
        }
    }
  };

  issue(0);
  for (int s = 0; s < NS1; ++s) {
    __syncthreads();
    write_lds();
    __syncthreads();
    if (s + 1 < NS1) issue(s + 1);
    compute();
  }

  #pragma unroll
  for (int i = 0; i < 8; i++) {
    int row = rowBase + tr * 8 + i;
    f4 v0 = {acc[i][0], acc[i][1], acc[i][2], acc[i][3]};
    f4 v1 = {acc[i][4], acc[i][5], acc[i][6], acc[i][7]};
    *(f4*)&IO[(size_t)row * COUT + oc0 + tc * 4] = v0;
    *(f4*)&IO[(size_t)row * COUT + oc0 + 64 + tc * 4] = v1;
  }
}

// ---------------- layer-1 scan ----------------

__global__ __launch_bounds__(256)
void scan1_k(const float* __restrict__ IO, const float* __restrict__ b1v,
             const float* __restrict__ vth1,
             unsigned char* __restrict__ SP,   // [4][NPIX][512] u8
             float* __restrict__ ACT)          // [NPIX][512]
{
  int idx = blockIdx.x * 256 + threadIdx.x;
  int oc = idx & 511, pix = idx >> 9;
  int hw = pix % HWO;
  float b1 = b1v[oc], vt = vth1[oc * HWO + hw];
  float mem = 0.f; int m1 = 0;
  #pragma unroll
  for (int t = 0; t < 4; ++t) {
    float cur = IO[((size_t)t * NPIX + pix) * 512 + oc] + b1;
    mem += cur;
    float sp = (mem >= vt) ? 1.f : 0.f;
    mem -= sp * vt;
    m1 += (sp > 0.f) ? 1 : 0;
    SP[((size_t)t * NPIX + pix) * 512 + oc] = (unsigned char)sp;
  }
  float a = IO[((size_t)4 * NPIX + pix) * 512 + oc] + b1;
  a = a > 0.f ? a : 0.f;
  ACT[(size_t)pix * 512 + oc] = (m1 > 0) ? a : 0.f;
}

// ---------------- conv2 batched (3x3 s1 p1) + ds (1x1 s2) fused ----------------

__global__ __launch_bounds__(256)
void conv2b_k(const unsigned char* __restrict__ SP,
              const float* __restrict__ ACT,
              const float* __restrict__ XS,
              const float* __restrict__ XC,
              const float* __restrict__ W2,
              const float* __restrict__ WD,
              float* __restrict__ IO)
{
  __shared__ float lA[BKC * LRA];
  __shared__ float lW[BKC * LRW];
  const int tid = threadIdx.x;
  const int tr = tid >> 4;
  const int tc = tid & 15;
  const int oc0 = blockIdx.x * BNcT;
  const int rowBase = blockIdx.y * BMr;
  const int app = blockIdx.y / 49;

  const int grow = tid & 127;
  const int kq = tid >> 7;
  const int r = rowBase + grow;
  const int pp = r - app * NPIX;
  const int b = pp / HWO;
  const int hw = pp - b * HWO;
  const int ho = hw / WO, wo = hw - ho * WO;
  const float* xb = (app < 4) ? (XS + (size_t)(app * 32 + b) * (CIN * 784))
                              : (XC + (size_t)b * (CIN * 784));
  const unsigned char* spb = SP + (size_t)app * NPIX * 512;

  const int wk = tid >> 4;
  const int woc = (tid & 15) * 8;

  float acc[8][8];
  #pragma unroll
  for (int i = 0; i < 8; i++)
    #pragma unroll
    for (int j = 0; j < 8; j++) acc[i][j] = 0.f;

  float ga[8]; f4 gw0, gw1;

  auto issue = [&](int s) {
    if (s < 288) {
      int tap = s >> 5, c0 = (s & 31) << 4;
      int kh = tap / 3, kw = tap - kh * 3;
      int hi = ho + kh - 1, wi = wo + kw - 1;
      bool v = ((unsigned)hi < (unsigned)HO) && ((unsigned)wi < (unsigned)WO);
      int pix2 = b * HWO + hi * WO + wi;
      int c = c0 + kq * 8;
      if (app < 4) {
        unsigned u0 = 0, u1 = 0;
        if (v) {
          const unsigned* sp32 = (const unsigned*)(spb + (size_t)pix2 * 512 + c);
          u0 = sp32[0]; u1 = sp32[1];
        }
        #pragma unroll
        for (int j = 0; j < 4; j++) {
          ga[j]     = (float)((u0 >> (8 * j)) & 255u);
          ga[j + 4] = (float)((u1 >> (8 * j)) & 255u);
        }
      } else {
        f4 v0 = {0.f,0.f,0.f,0.f}, v1 = {0.f,0.f,0.f,0.f};
        if (v) {
          const float* ap = ACT + (size_t)pix2 * 512 + c;
          v0 = *(const f4*)ap; v1 = *(const f4*)(ap + 4);
        }
        #pragma unroll
        for (int j = 0; j < 4; j++) { ga[j] = v0[j]; ga[j + 4] = v1[j]; }
      }
      const float* wp = W2 + ((size_t)tap * COUT + c0 + wk) * COUT + oc0 + woc;
      gw0 = *(const f4*)wp;
      gw1 = *(const f4*)(wp + 4);
    } else {
      int c0 = (s - 288) << 4;
      const float* xp = xb + (size_t)(c0 + kq * 8) * 784 + 2 * ho * WIN_ + 2 * wo;
      #pragma unroll
      for (int j = 0; j < 8; j++) ga[j] = xp[(size_t)j * 784];
      const float* wp = WD + (size_t)(c0 + wk) * COUT + oc0 + woc;
      gw0 = *(const f4*)wp;
      gw1 = *(const f4*)(wp + 4);
    }
  };

  auto write_lds = [&]() {
    #pragma unroll
    for (int j = 0; j < 8; j++) lA[(kq * 8 + j) * LRA + grow] = ga[j];
    *(f4*)&lW[wk * LRW + woc] = gw0;
    *(f4*)&lW[wk * LRW + woc + 4] = gw1;
  };

  auto compute = [&]() {
    #pragma unroll
    for (int k = 0; k < BKC; k++) {
      f4 a0 = *(const f4*)&lA[k * LRA + tr * 8];
      f4 a1 = *(const f4*)&lA[k * LRA + tr * 8 + 4];
      f4 w0 = *(const f4*)&lW[k * LRW + tc * 4];
      f4 w1 = *(const f4*)&lW[k * LRW + 64 + tc * 4];
      #pragma unroll
      for (int i = 0; i < 4; i++)
        #pragma unroll
        for (int j = 0; j < 4; j++) {
          acc[i][j]         = fmaf(a0[i], w0[j], acc[i][j]);
          acc[i][j + 4]     = fmaf(a0[i], w1[j], acc[i][j + 4]);
          acc[i + 4][j]     = fmaf(a1[i], w0[j], acc[i + 4][j]);
          acc[i + 4][j + 4] = fmaf(a1[i], w1[j], acc[i + 4][j + 4]);
        }
    }
  };

  issue(0);
  for (int s = 0; s < NS2; ++s) {
    __syncthreads();
    write_lds();
    __syncthreads();
    if (s + 1 < NS2) issue(s + 1);
    compute();
  }

  #pragma unroll
  for (int i = 0; i < 8; i++) {
    int row = rowBase + tr * 8 + i;
    f4 v0 = {acc[i][0], acc[i][1], acc[i][2], acc[i][3]};
    f4 v1 = {acc[i][4], acc[i][5], acc[i][6], acc[i][7]};
    *(f4*)&IO[(size_t)row * COUT + oc0 + tc * 4] = v0;
    *(f4*)&IO[(size_t)row * COUT + oc0 + 64 + tc * 4] = v1;
  }
}

// ---------------- final scan + outputs (NCHW) ----------------

__global__ __launch_bounds__(256)
void final_k(const float* __restrict__ IO, const float* __restrict__ b2v,
             const float* __restrict__ bdv, const float* __restrict__ vthif,
             float* __restrict__ out0, float* __restrict__ out1,
             float* __restrict__ out2)
{
  int idx = blockIdx.x * 256 + threadIdx.x;
  int oc = idx & 511, pix = idx >> 9;
  int hw = pix % HWO, b = pix / HWO;
  float bias = b2v[oc] + bdv[oc];
  float vt = vthif[oc * HWO + hw];
  float memf = 0.f; int m3 = 0; float o3 = 0.f, os3 = 0.f;
  #pragma unroll
  for (int t = 0; t < 4; ++t) {
    float os = IO[((size_t)t * NPIX + pix) * 512 + oc] + bias;
    memf += os;
    float sp = (memf >= vt) ? 1.f : 0.f;
    memf -= sp * vt;
    m3 += (sp > 0.f) ? 1 : 0;
    if (t == 3) { o3 = sp; os3 = os; }
  }
  size_t oidx = ((size_t)b * COUT + oc) * HWO + hw;
  out0[oidx] = o3;
  out1[oidx] = os3;
  float av = IO[((size_t)4 * NPIX + pix) * 512 + oc] + bias;
  av = av > 0.f ? av : 0.f;
  out2[oidx] = (m3 > 0) ? av : 0.f;
}

// ---------------- launcher ----------------

extern "C" void kernel_launch(void* const* d_in, const int* in_sizes, int n_in,
                              void* d_out, int out_size, void* d_ws, size_t ws_size,
                              hipStream_t stream)
{
  const float* inp_s = (const float*)d_in[0];
  const float* inp_c = (const float*)d_in[2];
  const float* w1    = (const float*)d_in[3];
  const float* w2    = (const float*)d_in[4];
  const float* wd    = (const float*)d_in[5];
  const float* bn1g = (const float*)d_in[6],  *bn1b = (const float*)d_in[7];
  const float* bn1m = (const float*)d_in[8],  *bn1v = (const float*)d_in[9];
  const float* bn2g = (const float*)d_in[10], *bn2b = (const float*)d_in[11];
  const float* bn2m = (const float*)d_in[12], *bn2v = (const float*)d_in[13];
  const float* dsg  = (const float*)d_in[14], *dsb  = (const float*)d_in[15];
  const float* dsm  = (const float*)d_in[16], *dsv  = (const float*)d_in[17];
  const float* vth1  = (const float*)d_in[18];
  const float* vthif = (const float*)d_in[21];

  float* ws = (float*)d_ws;
  size_t off = 0;
  float* W1T = ws + off; off += (size_t)9 * CIN * COUT;
  float* W2T = ws + off; off += (size_t)9 * COUT * COUT;
  float* WDT = ws + off; off += (size_t)CIN * COUT;
  float* B1V = ws + off; off += COUT;
  float* B2V = ws + off; off += COUT;
  float* BDV = ws + off; off += COUT;
  float* IO  = ws + off; off += (size_t)MROWS * COUT;
  float* ACT = ws + off; off += (size_t)NPIX * COUT;
  unsigned char* SP = (unsigned char*)(ws + off);
  // total ~104.6 MB, under the R1-proven 117.4 MB bound

  float* out0 = (float*)d_out;
  float* out1 = out0 + (size_t)NPIX * COUT;
  float* out2 = out1 + (size_t)NPIX * COUT;

  fold_bias_k<<<2, 256, 0, stream>>>(bn1g, bn1b, bn1m, bn1v, B1V);
  fold_bias_k<<<2, 256, 0, stream>>>(bn2g, bn2b, bn2m, bn2v, B2V);
  fold_bias_k<<<2, 256, 0, stream>>>(dsg,  dsb,  dsm,  dsv,  BDV);
  fold_w_k<<<(9 * CIN * COUT + 255) / 256, 256, 0, stream>>>(w1, bn1g, bn1v, W1T, CIN, 9);
  fold_w_k<<<(9 * COUT * COUT + 255) / 256, 256, 0, stream>>>(w2, bn2g, bn2v, W2T, COUT, 9);
  fold_w_k<<<(CIN * COUT + 255) / 256, 256, 0, stream>>>(wd, dsg, dsv, WDT, CIN, 1);

  dim3 cgrid(COUT / BNcT, MROWS / BMr);         // 4 x 245
  const int scanGrid = (NPIX * COUT) / 256;

  conv1b_k<<<cgrid, 256, 0, stream>>>(inp_s, inp_c, W1T, IO);
  scan1_k<<<scanGrid, 256, 0, stream>>>(IO, B1V, vth1, SP, ACT);
  conv2b_k<<<cgrid, 256, 0, stream>>>(SP, ACT, inp_s, inp_c, W2T, WDT, IO);
  final_k<<<scanGrid, 256, 0, stream>>>(IO, B2V, BDV, vthif, out0, out1, out2);
}

// Round 20
// 2756.203 us; speedup vs baseline: 1.0549x; 1.0024x over previous
//
#include <hip/hip_runtime.h>

typedef float f4 __attribute__((ext_vector_type(4)));

#define EPSF 1e-5f
#define CIN   256
#define COUT  512
#define HIN   28
#define WIN_  28
#define HO    14
#define WO    14
#define HWO   196
#define NPIX  6272              // 32*14*14 (one app)
#define MROWS 31360             // 5 apps * NPIX

#define BMr  128                // rows per block
#define BNcT 128                // oc per block
#define BKC  16                 // k per step
#define LRA  128                // A[k][row] stride
#define LRW  132                // W[k][oc] stride (pad)

#define NS1  144                // conv1: 9 taps * 16 chunks of 16
#define NS2  304                // conv2: 288 conv + 16 ds

// ---------------- prep kernels ----------------

__global__ __launch_bounds__(256)
void fold_bias_k(const float* __restrict__ g, const float* __restrict__ b,
                 const float* __restrict__ m, const float* __restrict__ v,
                 float* __restrict__ out)
{
  int oc = blockIdx.x * 256 + threadIdx.x;
  if (oc < COUT) {
    float s = g[oc] / sqrtf(v[oc] + EPSF);
    out[oc] = b[oc] - m[oc] * s;
  }
}

__global__ __launch_bounds__(256)
void fold_w_k(const float* __restrict__ w, const float* __restrict__ g,
              const float* __restrict__ v, float* __restrict__ out,
              int Ci, int taps)
{
  int idx = blockIdx.x * 256 + threadIdx.x;
  int total = taps * Ci * COUT;
  if (idx >= total) return;
  int oc  = idx % COUT;
  int c   = (idx / COUT) % Ci;
  int tap = idx / (COUT * Ci);
  float s = g[oc] / sqrtf(v[oc] + EPSF);
  out[idx] = w[((size_t)oc * Ci + c) * taps + tap] * s;
}

// ---------------- conv1 batched over 5 apps (3x3 s2 p1) ----------------
// Register-tiled GEMM: 128x128 tile, thread = 8 rows x 8 oc.
// blockIdx.x = oc-tile (4); blockIdx.y = M-tile (245).

__global__ __launch_bounds__(256)
void conv1b_k(const float* __restrict__ XS,   // inp_s (4,32,256,28,28)
              const float* __restrict__ XC,   // inp_c (32,256,28,28)
              const float* __restrict__ W1,   // [tap][c][oc]
              float* __restrict__ IO)         // [31360][512]
{
  __shared__ float lA[BKC * LRA];
  __shared__ float lW[BKC * LRW];
  const int tid = threadIdx.x;
  const int tr = tid >> 4;          // 0..15 -> rows tr*8..+7
  const int tc = tid & 15;          // oc tc*4 and 64+tc*4
  const int oc0 = blockIdx.x * BNcT;
  const int rowBase = blockIdx.y * BMr;
  const int app = blockIdx.y / 49;  // block-uniform

  // A staging role: one row, 8 k values
  const int grow = tid & 127;
  const int kq = tid >> 7;          // 0..1 -> k = kq*8 + j
  const int r = rowBase + grow;
  const int pp = r - app * NPIX;
  const int b = pp / HWO;
  const int hw = pp - b * HWO;
  const int ho = hw / WO, wo = hw - ho * WO;
  const float* xb = (app < 4) ? (XS + (size_t)(app * 32 + b) * (CIN * 784))
                              : (XC + (size_t)b * (CIN * 784));

  // W staging role
  const int wk = tid >> 4;          // k row 0..15
  const int woc = (tid & 15) * 8;   // 8 oc

  float acc[8][8];
  #pragma unroll
  for (int i = 0; i < 8; i++)
    #pragma unroll
    for (int j = 0; j < 8; j++) acc[i][j] = 0.f;

  float ga[8]; f4 gw0, gw1;

  auto issue = [&](int s) {
    int tap = s >> 4, c0 = (s & 15) << 4;
    int kh = tap / 3, kw = tap - kh * 3;
    int hi = 2 * ho + kh - 1, wi = 2 * wo + kw - 1;
    bool v = ((unsigned)hi < (unsigned)HIN) && ((unsigned)wi < (unsigned)WIN_);
    const float* xp = xb + (size_t)(c0 + kq * 8) * 784 + hi * WIN_ + wi;
    #pragma unroll
    for (int j = 0; j < 8; j++) ga[j] = v ? xp[(size_t)j * 784] : 0.f;
    const float* wp = W1 + ((size_t)tap * CIN + c0 + wk) * COUT + oc0 + woc;
    gw0 = *(const f4*)wp;
    gw1 = *(const f4*)(wp + 4);
  };

  auto write_lds = [&]() {
    #pragma unroll
    for (int j = 0; j < 8; j++) lA[(kq * 8 + j) * LRA + grow] = ga[j];
    *(f4*)&lW[wk * LRW + woc] = gw0;
    *(f4*)&lW[wk * LRW + woc + 4] = gw1;
  };

  auto compute = [&]() {
    #pragma unroll
    for (int k = 0; k < BKC; k++) {
      f4 a0 = *(const f4*)&lA[k * LRA + tr * 8];
      f4 a1 = *(const f4*)&lA[k * LRA + tr * 8 + 4];
      f4 w0 = *(const f4*)&lW[k * LRW + tc * 4];
      f4 w1 = *(const f4*)&lW[k * LRW + 64 + tc * 4];
      #pragma unroll
      for (int i = 0; i < 4; i++)
        #pragma unroll
        for (int j = 0; j < 4; j++) {
          acc[i][j]         = fmaf(a0[i], w0[j], acc[i][j]);
          acc[i][j + 4]     = fmaf(a0[i], w1[j], acc[i][j + 4]);
          acc[i + 4][j]     = fmaf(a1[i], w0[j], acc[i + 4][j]);
          acc[i + 4][j + 4] = fmaf(a1[i], w1[j], acc[i + 4][j + 4]);
        }
    }
  };

  issue(0);
  for (int s = 0; s < NS1; ++s) {
    __syncthreads();
    write_lds();
    __syncthreads();
    if (s + 1 < NS1) issue(s + 1);
    compute();
  }

  #pragma unroll
  for (int i = 0; i < 8; i++) {
    int row = rowBase + tr * 8 + i;
    f4 v0 = {acc[i][0], acc[i][1], acc[i][2], acc[i][3]};
    f4 v1 = {acc[i][4], acc[i][5], acc[i][6], acc[i][7]};
    *(f4*)&IO[(size_t)row * COUT + oc0 + tc * 4] = v0;
    *(f4*)&IO[(size_t)row * COUT + oc0 + 64 + tc * 4] = v1;
  }
}

// ---------------- layer-1 scan ----------------

__global__ __launch_bounds__(256)
void scan1_k(const float* __restrict__ IO, const float* __restrict__ b1v,
             const float* __restrict__ vth1,
             unsigned char* __restrict__ SP,   // [4][NPIX][512] u8
             float* __restrict__ ACT)          // [NPIX][512]
{
  int idx = blockIdx.x * 256 + threadIdx.x;
  int oc = idx & 511, pix = idx >> 9;
  int hw = pix % HWO;
  float b1 = b1v[oc], vt = vth1[oc * HWO + hw];
  float mem = 0.f; int m1 = 0;
  #pragma unroll
  for (int t = 0; t < 4; ++t) {
    float cur = IO[((size_t)t * NPIX + pix) * 512 + oc] + b1;
    mem += cur;
    float sp = (mem >= vt) ? 1.f : 0.f;
    mem -= sp * vt;
    m1 += (sp > 0.f) ? 1 : 0;
    SP[((size_t)t * NPIX + pix) * 512 + oc] = (unsigned char)sp;
  }
  float a = IO[((size_t)4 * NPIX + pix) * 512 + oc] + b1;
  a = a > 0.f ? a : 0.f;
  ACT[(size_t)pix * 512 + oc] = (m1 > 0) ? a : 0.f;
}

// ---------------- conv2 batched (3x3 s1 p1) + ds (1x1 s2) fused ----------------

__global__ __launch_bounds__(256)
void conv2b_k(const unsigned char* __restrict__ SP,
              const float* __restrict__ ACT,
              const float* __restrict__ XS,
              const float* __restrict__ XC,
              const float* __restrict__ W2,
              const float* __restrict__ WD,
              float* __restrict__ IO)
{
  __shared__ float lA[BKC * LRA];
  __shared__ float lW[BKC * LRW];
  const int tid = threadIdx.x;
  const int tr = tid >> 4;
  const int tc = tid & 15;
  const int oc0 = blockIdx.x * BNcT;
  const int rowBase = blockIdx.y * BMr;
  const int app = blockIdx.y / 49;

  const int grow = tid & 127;
  const int kq = tid >> 7;
  const int r = rowBase + grow;
  const int pp = r - app * NPIX;
  const int b = pp / HWO;
  const int hw = pp - b * HWO;
  const int ho = hw / WO, wo = hw - ho * WO;
  const float* xb = (app < 4) ? (XS + (size_t)(app * 32 + b) * (CIN * 784))
                              : (XC + (size_t)b * (CIN * 784));
  const unsigned char* spb = SP + (size_t)app * NPIX * 512;

  const int wk = tid >> 4;
  const int woc = (tid & 15) * 8;

  float acc[8][8];
  #pragma unroll
  for (int i = 0; i < 8; i++)
    #pragma unroll
    for (int j = 0; j < 8; j++) acc[i][j] = 0.f;

  float ga[8]; f4 gw0, gw1;

  auto issue = [&](int s) {
    if (s < 288) {
      int tap = s >> 5, c0 = (s & 31) << 4;
      int kh = tap / 3, kw = tap - kh * 3;
      int hi = ho + kh - 1, wi = wo + kw - 1;
      bool v = ((unsigned)hi < (unsigned)HO) && ((unsigned)wi < (unsigned)WO);
      int pix2 = b * HWO + hi * WO + wi;
      int c = c0 + kq * 8;
      if (app < 4) {
        unsigned u0 = 0, u1 = 0;
        if (v) {
          const unsigned* sp32 = (const unsigned*)(spb + (size_t)pix2 * 512 + c);
          u0 = sp32[0]; u1 = sp32[1];
        }
        #pragma unroll
        for (int j = 0; j < 4; j++) {
          ga[j]     = (float)((u0 >> (8 * j)) & 255u);
          ga[j + 4] = (float)((u1 >> (8 * j)) & 255u);
        }
      } else {
        f4 v0 = {0.f,0.f,0.f,0.f}, v1 = {0.f,0.f,0.f,0.f};
        if (v) {
          const float* ap = ACT + (size_t)pix2 * 512 + c;
          v0 = *(const f4*)ap; v1 = *(const f4*)(ap + 4);
        }
        #pragma unroll
        for (int j = 0; j < 4; j++) { ga[j] = v0[j]; ga[j + 4] = v1[j]; }
      }
      const float* wp = W2 + ((size_t)tap * COUT + c0 + wk) * COUT + oc0 + woc;
      gw0 = *(const f4*)wp;
      gw1 = *(const f4*)(wp + 4);
    } else {
      int c0 = (s - 288) << 4;
      const float* xp = xb + (size_t)(c0 + kq * 8) * 784 + 2 * ho * WIN_ + 2 * wo;
      #pragma unroll
      for (int j = 0; j < 8; j++) ga[j] = xp[(size_t)j * 784];
      const float* wp = WD + (size_t)(c0 + wk) * COUT + oc0 + woc;
      gw0 = *(const f4*)wp;
      gw1 = *(const f4*)(wp + 4);
    }
  };

  auto write_lds = [&]() {
    #pragma unroll
    for (int j = 0; j < 8; j++) lA[(kq * 8 + j) * LRA + grow] = ga[j];
    *(f4*)&lW[wk * LRW + woc] = gw0;
    *(f4*)&lW[wk * LRW + woc + 4] = gw1;
  };

  auto compute = [&]() {
    #pragma unroll
    for (int k = 0; k < BKC; k++) {
      f4 a0 = *(const f4*)&lA[k * LRA + tr * 8];
      f4 a1 = *(const f4*)&lA[k * LRA + tr * 8 + 4];
      f4 w0 = *(const f4*)&lW[k * LRW + tc * 4];
      f4 w1 = *(const f4*)&lW[k * LRW + 64 + tc * 4];
      #pragma unroll
      for (int i = 0; i < 4; i++)
        #pragma unroll
        for (int j = 0; j < 4; j++) {
          acc[i][j]         = fmaf(a0[i], w0[j], acc[i][j]);
          acc[i][j + 4]     = fmaf(a0[i], w1[j], acc[i][j + 4]);
          acc[i + 4][j]     = fmaf(a1[i], w0[j], acc[i + 4][j]);
          acc[i + 4][j + 4] = fmaf(a1[i], w1[j], acc[i + 4][j + 4]);
        }
    }
  };

  issue(0);
  for (int s = 0; s < NS2; ++s) {
    __syncthreads();
    write_lds();
    __syncthreads();
    if (s + 1 < NS2) issue(s + 1);
    compute();
  }

  #pragma unroll
  for (int i = 0; i < 8; i++) {
    int row = rowBase + tr * 8 + i;
    f4 v0 = {acc[i][0], acc[i][1], acc[i][2], acc[i][3]};
    f4 v1 = {acc[i][4], acc[i][5], acc[i][6], acc[i][7]};
    *(f4*)&IO[(size_t)row * COUT + oc0 + tc * 4] = v0;
    *(f4*)&IO[(size_t)row * COUT + oc0 + 64 + tc * 4] = v1;
  }
}

// ---------------- final scan + outputs (NCHW) ----------------

__global__ __launch_bounds__(256)
void final_k(const float* __restrict__ IO, const float* __restrict__ b2v,
             const float* __restrict__ bdv, const float* __restrict__ vthif,
             float* __restrict__ out0, float* __restrict__ out1,
             float* __restrict__ out2)
{
  int idx = blockIdx.x * 256 + threadIdx.x;
  int oc = idx & 511, pix = idx >> 9;
  int hw = pix % HWO, b = pix / HWO;
  float bias = b2v[oc] + bdv[oc];
  float vt = vthif[oc * HWO + hw];
  float memf = 0.f; int m3 = 0; float o3 = 0.f, os3 = 0.f;
  #pragma unroll
  for (int t = 0; t < 4; ++t) {
    float os = IO[((size_t)t * NPIX + pix) * 512 + oc] + bias;
    memf += os;
    float sp = (memf >= vt) ? 1.f : 0.f;
    memf -= sp * vt;
    m3 += (sp > 0.f) ? 1 : 0;
    if (t == 3) { o3 = sp; os3 = os; }
  }
  size_t oidx = ((size_t)b * COUT + oc) * HWO + hw;
  out0[oidx] = o3;
  out1[oidx] = os3;
  float av = IO[((size_t)4 * NPIX + pix) * 512 + oc] + bias;
  av = av > 0.f ? av : 0.f;
  out2[oidx] = (m3 > 0) ? av : 0.f;
}

// ---------------- launcher ----------------

extern "C" void kernel_launch(void* const* d_in, const int* in_sizes, int n_in,
                              void* d_out, int out_size, void* d_ws, size_t ws_size,
                              hipStream_t stream)
{
  const float* inp_s = (const float*)d_in[0];
  const float* inp_c = (const float*)d_in[2];
  const float* w1    = (const float*)d_in[3];
  const float* w2    = (const float*)d_in[4];
  const float* wd    = (const float*)d_in[5];
  const float* bn1g = (const float*)d_in[6],  *bn1b = (const float*)d_in[7];
  const float* bn1m = (const float*)d_in[8],  *bn1v = (const float*)d_in[9];
  const float* bn2g = (const float*)d_in[10], *bn2b = (const float*)d_in[11];
  const float* bn2m = (const float*)d_in[12], *bn2v = (const float*)d_in[13];
  const float* dsg  = (const float*)d_in[14], *dsb  = (const float*)d_in[15];
  const float* dsm  = (const float*)d_in[16], *dsv  = (const float*)d_in[17];
  const float* vth1  = (const float*)d_in[18];
  const float* vthif = (const float*)d_in[21];

  float* ws = (float*)d_ws;
  size_t off = 0;
  float* W1T = ws + off; off += (size_t)9 * CIN * COUT;
  float* W2T = ws + off; off += (size_t)9 * COUT * COUT;
  float* WDT = ws + off; off += (size_t)CIN * COUT;
  float* B1V = ws + off; off += COUT;
  float* B2V = ws + off; off += COUT;
  float* BDV = ws + off; off += COUT;
  float* IO  = ws + off; off += (size_t)MROWS * COUT;
  float* ACT = ws + off; off += (size_t)NPIX * COUT;
  unsigned char* SP = (unsigned char*)(ws + off);
  // total ~104.6 MB, under the R1-proven 117.4 MB bound

  float* out0 = (float*)d_out;
  float* out1 = out0 + (size_t)NPIX * COUT;
  float* out2 = out1 + (size_t)NPIX * COUT;

  fold_bias_k<<<2, 256, 0, stream>>>(bn1g, bn1b, bn1m, bn1v, B1V);
  fold_bias_k<<<2, 256, 0, stream>>>(bn2g, bn2b, bn2m, bn2v, B2V);
  fold_bias_k<<<2, 256, 0, stream>>>(dsg,  dsb,  dsm,  dsv,  BDV);
  fold_w_k<<<(9 * CIN * COUT + 255) / 256, 256, 0, stream>>>(w1, bn1g, bn1v, W1T, CIN, 9);
  fold_w_k<<<(9 * COUT * COUT + 255) / 256, 256, 0, stream>>>(w2, bn2g, bn2v, W2T, COUT, 9);
  fold_w_k<<<(CIN * COUT + 255) / 256, 256, 0, stream>>>(wd, dsg, dsv, WDT, CIN, 1);

  dim3 cgrid(COUT / BNcT, MROWS / BMr);         // 4 x 245
  const int scanGrid = (NPIX * COUT) / 256;

  conv1b_k<<<cgrid, 256, 0, stream>>>(inp_s, inp_c, W1T, IO);
  scan1_k<<<scanGrid, 256, 0, stream>>>(IO, B1V, vth1, SP, ACT);
  conv2b_k<<<cgrid, 256, 0, stream>>>(SP, ACT, inp_s, inp_c, W2T, WDT, IO);
  final_k<<<scanGrid, 256, 0, stream>>>(IO, B2V, BDV, vthif, out0, out1, out2);
}